// Round 4
// baseline (138.464 us; speedup 1.0000x reference)
//
#include <hip/hip_runtime.h>
#include <stdint.h>

typedef __bf16 bf16x8 __attribute__((ext_vector_type(8)));
typedef float  f32x4  __attribute__((ext_vector_type(4)));
typedef uint32_t u32x4 __attribute__((ext_vector_type(4)));

__device__ __forceinline__ uint16_t f2bf(float f) {
    uint32_t u = __builtin_bit_cast(uint32_t, f);
    u += 0x7FFFu + ((u >> 16) & 1u);          // round-to-nearest-even
    return (uint16_t)(u >> 16);
}

// ---------------------------------------------------------------------------
// Kernel 1: Q [b][c 256][i 32][j 32] f32 -> Qt [b][ih 2][j 32][ch 32][il 16][8] bf16
//   where c = ch*8 + t, i = ih*16 + il.  Corr's B-fragment load = 1 KB contiguous.
//   Also zeroes the output tensor (replaces the separate hipMemsetAsync).
// ---------------------------------------------------------------------------
__global__ __launch_bounds__(256) void qtrans_kernel(const float* __restrict__ Q,
                                                     uint16_t* __restrict__ Qt,
                                                     float* __restrict__ out) {
    // T[c8 8][i 32][j 33] f32, c8-stride 1064 so bank = 8*c8 + i + j
    __shared__ float T[8 * 1064];
    const int ch = blockIdx.x, b = blockIdx.y;
    const int tid = threadIdx.x;

    // fold in out-zeroing: 512 blocks x 256 threads = 131072 >= 67600
    {
        int g = (b * 32 + ch) * 256 + tid;
        if (g < 67600) out[g] = 0.f;
    }

    const float* src = Q + ((size_t)(b * 256 + ch * 8)) * 1024;
    #pragma unroll
    for (int it = 0; it < 32; ++it) {                  // 8192 f32, coalesced
        int r = tid + it * 256;
        int c8 = r >> 10, rem = r & 1023;
        T[c8 * 1064 + (rem >> 5) * 33 + (rem & 31)] = src[(size_t)c8 * 1024 + rem];
    }
    __syncthreads();

    uint32_t* dst = (uint32_t*)Qt;                     // write bf16 pairs
    #pragma unroll
    for (int it = 0; it < 16; ++it) {                  // 4096 pairs
        int o2 = tid + it * 256;
        int t  = (o2 & 3) * 2;
        int il = (o2 >> 2) & 15;
        int j  = (o2 >> 6) & 31;
        int ih = (o2 >> 11) & 1;
        float v0 = T[t * 1064 + (ih * 16 + il) * 33 + j];
        float v1 = T[(t + 1) * 1064 + (ih * 16 + il) * 33 + j];
        uint32_t pk = (uint32_t)f2bf(v0) | ((uint32_t)f2bf(v1) << 16);
        size_t oi = ((((size_t)(b * 2 + ih) * 32 + j) * 32 + ch) * 16 + il) * 4 + (t >> 1);
        dst[oi] = pk;
    }
}

// ---------------------------------------------------------------------------
// Kernel 2: block = (b, d-pair, c-half).  bid -> b = bid&15 (XCD swizzle:
// per-XCD Qt set = 1 MB, L2-resident), dp = (bid>>4)&31, z = bid>>9.
// Each block computes BOTH d = 2dp and 2dp+1 for half the channels, so every
// Qt B-fragment read feeds 36 MFMAs instead of 18: total Qt L2 traffic halves
// (512 -> 256 MB).  Round-3 evidence: Qt stream ran at ~85% of the per-CU L2
// share -> queuing, MfmaUtil pinned at 32%.  This drops it to ~40%.
// LDS: S_l[sl 32][row 80][8] bf16, sl = dd*16 + local-ch-octet (exactly 40 KB,
// rows 0..15 zero-pad, OOB row-clamp to zero-row).  Pw overlay for epilogue.
// REGISTERS (round-2 lesson: AGPR shares the unified file): acc 80 + B 16 +
// A 20 + addr ~25 => ~140.  3 waves/SIMD budget = 170: __launch_bounds__(256,3).
// Do NOT request 4 -- it spills the accumulators.
// ---------------------------------------------------------------------------
__global__ __launch_bounds__(256, 3) void corr_kernel(const float* __restrict__ S,
                                                      const uint16_t* __restrict__ Qt,
                                                      float* __restrict__ out) {
    __shared__ __align__(16) char smem[40960];         // 40 KB
    uint16_t* S_l = (uint16_t*)smem;                   // idx = sl*640 + row*8
    float*    Pw  = (float*)smem;                      // overlay: [4][iv 32][x 80]

    const int bid = blockIdx.x;
    const int b = bid & 15, dp = (bid >> 4) & 31, z = bid >> 9;
    const int d0 = dp * 2;
    const int tid = threadIdx.x, wave = tid >> 6, lane = tid & 63;
    const int l15 = lane & 15, l4 = lane >> 4;

    // ---- zero-fill pad rows 0..15 for all 32 slabs (8 KB)
    {
        const u32x4 zz = {};
        #pragma unroll
        for (int zi = 0; zi < 2; ++zi) {
            int e = tid + zi * 256;
            int sl = e >> 4, r = e & 15;
            *(u32x4*)&S_l[(sl * 80 + r) * 8] = zz;
        }
    }
    // ---- stage S[b, z*128:(z+1)*128, d0:d0+2, :] -> bf16 slabs
    {
        const int sx = lane;
        const float* sp = S + ((size_t)(b * 256 + z * 128)) * 4096 + (size_t)d0 * 64 + sx;
        #pragma unroll
        for (int dd = 0; dd < 2; ++dd) {
            #pragma unroll
            for (int k = 0; k < 4; ++k) {
                const int ch = k * 4 + wave;           // local octet 0..15
                float v[8];
                #pragma unroll
                for (int cc = 0; cc < 8; ++cc)
                    v[cc] = sp[(size_t)(ch * 8 + cc) * 4096 + dd * 64];  // 256B coalesced
                u32x4 pk;
                #pragma unroll
                for (int q = 0; q < 4; ++q)
                    pk[q] = (uint32_t)f2bf(v[2 * q]) | ((uint32_t)f2bf(v[2 * q + 1]) << 16);
                *(u32x4*)&S_l[((dd * 16 + ch) * 80 + sx + 16) * 8] = pk;  // 1KB contig
            }
        }
    }
    __syncthreads();

    f32x4 acc0[5][2] = {};                             // d = d0
    f32x4 acc1[5][2] = {};                             // d = d0+1

    #pragma unroll
    for (int jj = 0; jj < 4; ++jj) {
        const int j0a = wave + jj * 4;                 // 0..15 ; j0b = j0a+16
        // global c-octet = z*16 + s*4 + l4
        const uint16_t* qa0 = Qt + (((size_t)b * 2 + 0) * 32 + j0a) * 4096
                                 + z * 2048 + l4 * 128 + l15 * 8;
        const uint16_t* qa1 = qa0 + 131072;            // ih = 1
        const uint16_t* qb0 = qa0 + 65536;             // j0b
        const uint16_t* qb1 = qa0 + 196608;            // ih=1, j0b

        int rof[5];
        #pragma unroll
        for (int t = 0; t < 5; ++t) {
            int rr = j0a + t * 16 + l15;               // <= 94
            rof[t] = ((rr < 80) ? rr : 0) * 8;         // OOB -> zero-row
        }

        #pragma unroll
        for (int s = 0; s < 4; ++s) {
            bf16x8 Ba0 = *(const bf16x8*)(qa0 + s * 512);
            bf16x8 Ba1 = *(const bf16x8*)(qa1 + s * 512);
            bf16x8 Bb0 = *(const bf16x8*)(qb0 + s * 512);
            bf16x8 Bb1 = *(const bf16x8*)(qb1 + s * 512);
            const int sb0 = (s * 4 + l4) * 640;        // d0 slab base
            const int sb1 = sb0 + 16 * 640;            // d1 slab base
            bf16x8 A[5];
            // ---- d0: 18 MFMA
            #pragma unroll
            for (int t = 0; t < 5; ++t)
                A[t] = *(const bf16x8*)&S_l[sb0 + rof[t]];       // conflict-free b128
            #pragma unroll
            for (int t = 0; t < 5; ++t) {
                acc0[t][0] = __builtin_amdgcn_mfma_f32_16x16x32_bf16(A[t], Ba0, acc0[t][0], 0, 0, 0);
                acc0[t][1] = __builtin_amdgcn_mfma_f32_16x16x32_bf16(A[t], Ba1, acc0[t][1], 0, 0, 0);
            }
            #pragma unroll
            for (int t = 1; t < 5; ++t) {
                acc0[t - 1][0] = __builtin_amdgcn_mfma_f32_16x16x32_bf16(A[t], Bb0, acc0[t - 1][0], 0, 0, 0);
                acc0[t - 1][1] = __builtin_amdgcn_mfma_f32_16x16x32_bf16(A[t], Bb1, acc0[t - 1][1], 0, 0, 0);
            }
            // ---- d1: 18 MFMA on the SAME B fragments
            #pragma unroll
            for (int t = 0; t < 5; ++t)
                A[t] = *(const bf16x8*)&S_l[sb1 + rof[t]];
            #pragma unroll
            for (int t = 0; t < 5; ++t) {
                acc1[t][0] = __builtin_amdgcn_mfma_f32_16x16x32_bf16(A[t], Ba0, acc1[t][0], 0, 0, 0);
                acc1[t][1] = __builtin_amdgcn_mfma_f32_16x16x32_bf16(A[t], Ba1, acc1[t][1], 0, 0, 0);
            }
            #pragma unroll
            for (int t = 1; t < 5; ++t) {
                acc1[t - 1][0] = __builtin_amdgcn_mfma_f32_16x16x32_bf16(A[t], Bb0, acc1[t - 1][0], 0, 0, 0);
                acc1[t - 1][1] = __builtin_amdgcn_mfma_f32_16x16x32_bf16(A[t], Bb1, acc1[t - 1][1], 0, 0, 0);
            }
        }
    }

    // ---- epilogue: two passes (d0 then d1), 40 KB Pw overlay each
    __syncthreads();
    #pragma unroll
    for (int dd = 0; dd < 2; ++dd) {
        {
            float* pw = Pw + wave * 2560;              // [iv 32][x 80]
            #pragma unroll
            for (int m = 0; m < 5; ++m)
                #pragma unroll
                for (int n = 0; n < 2; ++n)
                    *(f32x4*)&pw[(n * 16 + l15) * 80 + m * 16 + l4 * 4] =
                        dd ? acc1[m][n] : acc0[m][n];  // dd is compile-time (unrolled)
        }
        __syncthreads();
        const int d = d0 + dd;
        for (int e = tid; e < 65 * 32; e += 256) {
            int x = e % 65, i = e / 65;
            int y = d - i + 16;
            if ((unsigned)y < 65u) {
                float v = Pw[0 * 2560 + i * 80 + x] + Pw[1 * 2560 + i * 80 + x]
                        + Pw[2 * 2560 + i * 80 + x] + Pw[3 * 2560 + i * 80 + x];
                atomicAdd(out + ((size_t)b * 4225 + (size_t)y * 65 + x), v);
            }
        }
        __syncthreads();
    }
}

// ---------------------------------------------------------------------------
// fp32 fallback (only if workspace is too small) — slow but exact
// ---------------------------------------------------------------------------
__global__ __launch_bounds__(256) void naive_kernel(const float* __restrict__ Q,
                                                    const float* __restrict__ S,
                                                    float* __restrict__ out) {
    int gid = blockIdx.x * 256 + threadIdx.x;
    if (gid >= 67600) return;
    int b = gid / 4225, r = gid % 4225, y = r / 65, x = r % 65;
    int jlo = 16 - x; if (jlo < 0) jlo = 0;
    int jhi = 80 - x; if (jhi > 32) jhi = 32;
    float acc = 0.f;
    for (int c = 0; c < 256; ++c) {
        const float* Sb = S + ((size_t)(b * 256 + c)) * 4096;
        const float* Qb = Q + ((size_t)(b * 256 + c)) * 1024;
        for (int i = 0; i < 32; ++i) {
            int dd = y + i - 16;
            if ((unsigned)dd >= 64u) continue;
            const float* Sr = Sb + dd * 64 + (x - 16);
            const float* Qr = Qb + i * 32;
            for (int j = jlo; j < jhi; ++j) acc += Sr[j] * Qr[j];
        }
    }
    out[gid] = acc;
}

extern "C" void kernel_launch(void* const* d_in, const int* in_sizes, int n_in,
                              void* d_out, int out_size, void* d_ws, size_t ws_size,
                              hipStream_t stream) {
    (void)in_sizes; (void)n_in; (void)out_size;
    const float* Q = (const float*)d_in[0];   // [16,256,32,32] f32
    const float* S = (const float*)d_in[1];   // [16,256,64,64] f32
    float* out = (float*)d_out;               // [16,1,65,65] f32

    const size_t QT_BYTES = (size_t)16 * 2 * 32 * 32 * 16 * 8 * 2;  // 8,388,608

    if (ws_size < QT_BYTES) {
        naive_kernel<<<(67600 + 255) / 256, 256, 0, stream>>>(Q, S, out);
        return;
    }
    uint16_t* Qt = (uint16_t*)d_ws;

    qtrans_kernel<<<dim3(32, 16), 256, 0, stream>>>(Q, Qt, out);
    corr_kernel<<<1024, 256, 0, stream>>>(S, Qt, out);
}